// Round 5
// baseline (433.133 us; speedup 1.0000x reference)
//
#include <hip/hip_runtime.h>

#define N_NODES 100000
#define N_EDGES 1000000
#define D 64
#define NB 196        // buckets of 512 dst nodes: 196*512 = 100352 >= N_NODES
#define SUBCAP 1024   // per (bucket, sub) capacity; mean 640, +15 sigma safe
#define BSTAGE 6144   // per-bucket col stage; mean 5120, +14 sigma safe

// ---------------- phase A: bin edges by dst bucket ----------------
// pack = (src << 9) | (dst & 511); sub-bucket by blockIdx&7 keeps each append
// region XCD-local (round-robin dispatch heuristic) -> full-line writebacks.
__global__ void __launch_bounds__(256)
k_bucketA(const int* __restrict__ ei, int* __restrict__ subcur,
          int* __restrict__ pairs) {
    int e = blockIdx.x * blockDim.x + threadIdx.x;
    if (e >= N_EDGES) return;
    int s = ei[e];
    int d = ei[N_EDGES + e];
    int slot = ((d >> 9) << 3) | (blockIdx.x & 7);
    int p = atomicAdd(&subcur[slot], 1);
    if (p < SUBCAP) pairs[slot * SUBCAP + p] = (s << 9) | (d & 511);
}

// ---------------- bucket-level exclusive scan (1 block) ----------------
__global__ void k_bscan(const int* __restrict__ subcur, int* __restrict__ bucket_base) {
    __shared__ int tot[256];
    int t = threadIdx.x;
    int sum = 0;
    if (t < NB) {
        for (int s = 0; s < 8; s++) sum += min(subcur[t * 8 + s], SUBCAP);
    }
    tot[t] = sum;
    __syncthreads();
    for (int off = 1; off < 256; off <<= 1) {
        int v = (t >= off) ? tot[t - off] : 0;
        __syncthreads();
        tot[t] += v;
        __syncthreads();
    }
    if (t < NB) bucket_base[t] = (t == 0) ? 0 : tot[t - 1];
    if (t == NB - 1) bucket_base[NB] = tot[t];
}

// ---------------- phase B: per-bucket local counting sort ----------------
// one block per bucket: LDS histogram -> LDS scan -> row_start/inv_cnt ->
// place srcs in LDS stage -> coalesced dump to col.
__global__ void __launch_bounds__(256)
k_bucketB(const int* __restrict__ subcur, const int* __restrict__ pairs,
          const int* __restrict__ bucket_base, int* __restrict__ col,
          int* __restrict__ row_start, float* __restrict__ invc) {
    __shared__ int ldeg[512];
    __shared__ int lpos[512];
    __shared__ int lcur[512];
    __shared__ int sc[256];
    __shared__ int cnt[8];
    __shared__ int stage[BSTAGE];
    int b = blockIdx.x, t = threadIdx.x;
    if (t < 8) cnt[t] = min(subcur[b * 8 + t], SUBCAP);
    for (int i = t; i < 512; i += 256) ldeg[i] = 0;
    __syncthreads();
    // histogram of local dst
    for (int s = 0; s < 8; s++) {
        int c = cnt[s];
        const int* base = pairs + (size_t)(b * 8 + s) * SUBCAP;
        for (int i = t; i < c; i += 256) atomicAdd(&ldeg[base[i] & 511], 1);
    }
    __syncthreads();
    // exclusive scan of 512 degs (pair-sum + 256-wide Hillis-Steele)
    int a0 = ldeg[2 * t], a1 = ldeg[2 * t + 1];
    sc[t] = a0 + a1;
    __syncthreads();
    for (int off = 1; off < 256; off <<= 1) {
        int v = (t >= off) ? sc[t - off] : 0;
        __syncthreads();
        sc[t] += v;
        __syncthreads();
    }
    int excl = (t == 0) ? 0 : sc[t - 1];
    lpos[2 * t] = excl;
    lpos[2 * t + 1] = excl + a0;
    lcur[2 * t] = excl;
    lcur[2 * t + 1] = excl + a0;
    __syncthreads();
    int bbase = bucket_base[b];
    int total = bucket_base[b + 1] - bbase;
    if (total > BSTAGE) total = BSTAGE;
    // row_start + inv_cnt
    int n0 = b * 512;
    for (int i = t; i < 512; i += 256) {
        int n = n0 + i;
        if (n < N_NODES) {
            row_start[n] = bbase + lpos[i];
            int dg = ldeg[i];
            invc[n] = 1.0f / (float)(dg > 0 ? dg : 1);
        }
    }
    if (b == 0 && t == 0) row_start[N_NODES] = bucket_base[NB];
    // placement into LDS stage
    for (int s = 0; s < 8; s++) {
        int c = cnt[s];
        const int* base = pairs + (size_t)(b * 8 + s) * SUBCAP;
        for (int i = t; i < c; i += 256) {
            int v = base[i];
            int p = atomicAdd(&lcur[v & 511], 1);
            if (p < BSTAGE) stage[p] = v >> 9;
        }
    }
    __syncthreads();
    // coalesced dump
    for (int i = t; i < total; i += 256) col[bbase + i] = stage[i];
}

// ---------------- aggregation: mean over in-neighbors ----------------
__global__ void __launch_bounds__(256)
k_agg(const float4* __restrict__ X4, const int* __restrict__ row_start,
      const int* __restrict__ col, const float* __restrict__ inv_cnt,
      float4* __restrict__ M4) {
    int t = blockIdx.x * blockDim.x + threadIdx.x;
    int sub = t & 15;          // feature quad within node
    int n = t >> 4;            // node id
    if (n >= N_NODES) return;
    int s = row_start[n];
    int e = row_start[n + 1];
    float4 acc = make_float4(0.f, 0.f, 0.f, 0.f);
    int j = s;
    for (; j + 4 <= e; j += 4) {
        int c0 = col[j + 0];
        int c1 = col[j + 1];
        int c2 = col[j + 2];
        int c3 = col[j + 3];
        float4 a = X4[(size_t)c0 * 16 + sub];
        float4 b = X4[(size_t)c1 * 16 + sub];
        float4 c = X4[(size_t)c2 * 16 + sub];
        float4 d = X4[(size_t)c3 * 16 + sub];
        acc.x += (a.x + b.x) + (c.x + d.x);
        acc.y += (a.y + b.y) + (c.y + d.y);
        acc.z += (a.z + b.z) + (c.z + d.z);
        acc.w += (a.w + b.w) + (c.w + d.w);
    }
    for (; j < e; j++) {
        float4 a = X4[(size_t)col[j] * 16 + sub];
        acc.x += a.x; acc.y += a.y; acc.z += a.z; acc.w += a.w;
    }
    float ic = inv_cnt[n];
    acc.x *= ic; acc.y *= ic; acc.z *= ic; acc.w *= ic;
    M4[(size_t)n * 16 + sub] = acc;
}

// ---------------- fused linear: out = M*Wl^T + X*Wr^T + b (opt relu) -------------
// lane = node (64 nodes/block), wave = 16 output channels; weights in LDS
// transposed (k-major, stride 68) -> wave-uniform ds_read_b128 broadcast.
#define WROW 68
__global__ void __launch_bounds__(256)
k_linear(const float4* __restrict__ Ma4, const float4* __restrict__ Xa4,
         const float* __restrict__ Wl, const float* __restrict__ Wr,
         const float* __restrict__ bias, float4* __restrict__ out4, int do_relu) {
    __shared__ float wlT[D * WROW];
    __shared__ float wrT[D * WROW];
    int t = threadIdx.x;
    for (int i = t; i < D * D; i += 256) {
        int oc = i >> 6, k = i & 63;
        wlT[k * WROW + oc] = Wl[i];
        wrT[k * WROW + oc] = Wr[i];
    }
    __syncthreads();

    int lane = t & 63;
    int ocb = (t >> 6) * 16;
    int n = blockIdx.x * 64 + lane;
    if (n >= N_NODES) return;

    const float4* mrow = Ma4 + (size_t)n * (D / 4);
    const float4* xrow = Xa4 + (size_t)n * (D / 4);

    float acc[16];
#pragma unroll
    for (int o = 0; o < 16; o++) acc[o] = bias[ocb + o];

#pragma unroll 4
    for (int k4 = 0; k4 < D / 4; k4++) {
        float4 mv = mrow[k4];
        float4 xv = xrow[k4];
        const float* mp = (const float*)&mv;
        const float* xp = (const float*)&xv;
#pragma unroll
        for (int j = 0; j < 4; j++) {
            int k = k4 * 4 + j;
            const float4* wl4 = (const float4*)&wlT[k * WROW + ocb];
            const float4* wr4 = (const float4*)&wrT[k * WROW + ocb];
            float mj = mp[j];
            float xj = xp[j];
#pragma unroll
            for (int og = 0; og < 4; og++) {
                float4 wlv = wl4[og];
                float4 wrv = wr4[og];
                acc[og * 4 + 0] = fmaf(mj, wlv.x, fmaf(xj, wrv.x, acc[og * 4 + 0]));
                acc[og * 4 + 1] = fmaf(mj, wlv.y, fmaf(xj, wrv.y, acc[og * 4 + 1]));
                acc[og * 4 + 2] = fmaf(mj, wlv.z, fmaf(xj, wrv.z, acc[og * 4 + 2]));
                acc[og * 4 + 3] = fmaf(mj, wlv.w, fmaf(xj, wrv.w, acc[og * 4 + 3]));
            }
        }
    }

    if (do_relu) {
#pragma unroll
        for (int o = 0; o < 16; o++) acc[o] = fmaxf(acc[o], 0.f);
    }
    float4* orow = out4 + (size_t)n * (D / 4) + ocb / 4;
#pragma unroll
    for (int og = 0; og < 4; og++) {
        orow[og] = make_float4(acc[og * 4 + 0], acc[og * 4 + 1],
                               acc[og * 4 + 2], acc[og * 4 + 3]);
    }
}

// ---------------- launch ----------------
extern "C" void kernel_launch(void* const* d_in, const int* in_sizes, int n_in,
                              void* d_out, int out_size, void* d_ws, size_t ws_size,
                              hipStream_t stream) {
    const float* x   = (const float*)d_in[0];
    const int*   ei  = (const int*)d_in[1];
    const float* W1l = (const float*)d_in[2];
    const float* b1  = (const float*)d_in[3];
    const float* W1r = (const float*)d_in[4];
    const float* W2l = (const float*)d_in[5];
    const float* b2  = (const float*)d_in[6];
    const float* W2r = (const float*)d_in[7];
    float* out = (float*)d_out;

    char* ws = (char*)d_ws;
    size_t off = 0;
    auto alloc = [&](size_t bytes) -> char* {
        char* p = ws + off;
        off = (off + bytes + 255) & ~(size_t)255;
        return p;
    };
    int*   row_start   = (int*)alloc((size_t)(N_NODES + 1) * 4);
    int*   col         = (int*)alloc((size_t)N_EDGES * 4);
    float* invc        = (float*)alloc((size_t)N_NODES * 4);
    int*   subcur      = (int*)alloc((size_t)NB * 8 * 4);
    int*   bucket_base = (int*)alloc((size_t)(NB + 1) * 4);
    float* mbuf        = (float*)alloc((size_t)N_NODES * D * 4);
    float* hbuf        = (float*)alloc((size_t)N_NODES * D * 4);
    // pairs staging (6.4 MB) aliases mbuf (25.6 MB): consumed by k_bucketB
    // before k_agg writes mbuf. Keeps ws footprint at the proven size.
    int* pairs = (int*)mbuf;

    // CSR build via two-phase bucket sort (dense writes, no random scatter)
    hipMemsetAsync(subcur, 0, (size_t)NB * 8 * 4, stream);
    k_bucketA<<<(N_EDGES + 255) / 256, 256, 0, stream>>>(ei, subcur, pairs);
    k_bscan<<<1, 256, 0, stream>>>(subcur, bucket_base);
    k_bucketB<<<NB, 256, 0, stream>>>(subcur, pairs, bucket_base, col, row_start, invc);

    const int agg_blocks = (N_NODES * 16 + 255) / 256;   // 16 lanes per node
    const int lin_blocks = (N_NODES + 63) / 64;          // 64 nodes per block

    // layer 1
    k_agg<<<agg_blocks, 256, 0, stream>>>((const float4*)x, row_start, col, invc,
                                          (float4*)mbuf);
    k_linear<<<lin_blocks, 256, 0, stream>>>((const float4*)mbuf, (const float4*)x,
                                             W1l, W1r, b1, (float4*)hbuf, 1);
    // layer 2
    k_agg<<<agg_blocks, 256, 0, stream>>>((const float4*)hbuf, row_start, col, invc,
                                          (float4*)mbuf);
    k_linear<<<lin_blocks, 256, 0, stream>>>((const float4*)mbuf, (const float4*)hbuf,
                                             W2l, W2r, b2, (float4*)out, 0);
}

// Round 6
// 272.966 us; speedup vs baseline: 1.5868x; 1.5868x over previous
//
#include <hip/hip_runtime.h>

#define N_NODES 100000
#define N_EDGES 1000000
#define D 64
#define NB 196        // buckets of 512 dst nodes: 196*512 = 100352 >= N_NODES
#define SUBCAP 1024   // per (bucket, sub) capacity; mean ~640, ~15 sigma safe
#define BSTAGE 6144   // per-bucket col stage; mean 5120, ~14 sigma safe
#define CHUNK 4096    // edges per phase-A block
#define ABLOCKS ((N_EDGES + CHUNK - 1) / CHUNK)   // 245

// ---------------- phase A: block-local counting sort by dst bucket ----------------
// LDS histogram -> LDS scan -> ONE global atomic per (block,bucket) reserving a
// contiguous run -> LDS-sorted stage -> coalesced dump (runs of ~21 per bucket).
__global__ void __launch_bounds__(256)
k_bucketA(const int* __restrict__ ei, int* __restrict__ subcur,
          int* __restrict__ pairs) {
    __shared__ int hist[256];
    __shared__ int sc[256];
    __shared__ int lpos[NB];
    __shared__ int lcur[NB];
    __shared__ int gbase[NB];
    __shared__ int stage[CHUNK];
    __shared__ int astage[CHUNK];
    int t = threadIdx.x, blk = blockIdx.x;
    int sub = blk & 7;
    int e0 = blk * CHUNK;
    int e1 = min(e0 + CHUNK, N_EDGES);
    int cnt = e1 - e0;

    hist[t] = 0;
    __syncthreads();
    // pass 1: histogram of dst buckets
    for (int i = t; i < cnt; i += 256) {
        int d = ei[N_EDGES + e0 + i];
        atomicAdd(&hist[d >> 9], 1);
    }
    __syncthreads();
    // exclusive scan over 256 (NB=196 used)
    int h = hist[t];
    sc[t] = h;
    __syncthreads();
    for (int off = 1; off < 256; off <<= 1) {
        int v = (t >= off) ? sc[t - off] : 0;
        __syncthreads();
        sc[t] += v;
        __syncthreads();
    }
    if (t < NB) {
        int excl = sc[t] - h;
        lpos[t] = excl;
        lcur[t] = excl;
        // bulk reservation: one global atomic per (block,bucket)
        gbase[t] = (h > 0) ? atomicAdd(&subcur[(t << 3) | sub], h) : 0;
    }
    __syncthreads();
    // pass 2: place packed edges into bucket-sorted LDS stage + final address
    for (int i = t; i < cnt; i += 256) {
        int s = ei[e0 + i];
        int d = ei[N_EDGES + e0 + i];
        int b = d >> 9;
        int p = atomicAdd(&lcur[b], 1);
        int o = gbase[b] + (p - lpos[b]);
        stage[p] = (s << 9) | (d & 511);
        astage[p] = (o < SUBCAP) ? (((b << 3) | sub) * SUBCAP + o) : -1;
    }
    __syncthreads();
    // coalesced dump: consecutive stage entries of a bucket -> consecutive addrs
    for (int i = t; i < cnt; i += 256) {
        int a = astage[i];
        if (a >= 0) pairs[a] = stage[i];
    }
}

// ---------------- bucket-level exclusive scan (1 block) ----------------
__global__ void k_bscan(const int* __restrict__ subcur, int* __restrict__ bucket_base) {
    __shared__ int tot[256];
    int t = threadIdx.x;
    int sum = 0;
    if (t < NB) {
        for (int s = 0; s < 8; s++) sum += min(subcur[t * 8 + s], SUBCAP);
    }
    tot[t] = sum;
    __syncthreads();
    for (int off = 1; off < 256; off <<= 1) {
        int v = (t >= off) ? tot[t - off] : 0;
        __syncthreads();
        tot[t] += v;
        __syncthreads();
    }
    if (t < NB) bucket_base[t] = (t == 0) ? 0 : tot[t - 1];
    if (t == NB - 1) bucket_base[NB] = tot[t];
}

// ---------------- phase B: per-bucket local counting sort ----------------
__global__ void __launch_bounds__(256)
k_bucketB(const int* __restrict__ subcur, const int* __restrict__ pairs,
          const int* __restrict__ bucket_base, int* __restrict__ col,
          int* __restrict__ row_start, float* __restrict__ invc) {
    __shared__ int ldeg[512];
    __shared__ int lpos[512];
    __shared__ int lcur[512];
    __shared__ int sc[256];
    __shared__ int cnt[8];
    __shared__ int stage[BSTAGE];
    int b = blockIdx.x, t = threadIdx.x;
    if (t < 8) cnt[t] = min(subcur[b * 8 + t], SUBCAP);
    for (int i = t; i < 512; i += 256) ldeg[i] = 0;
    __syncthreads();
    for (int s = 0; s < 8; s++) {
        int c = cnt[s];
        const int* base = pairs + (size_t)(b * 8 + s) * SUBCAP;
        for (int i = t; i < c; i += 256) atomicAdd(&ldeg[base[i] & 511], 1);
    }
    __syncthreads();
    int a0 = ldeg[2 * t], a1 = ldeg[2 * t + 1];
    sc[t] = a0 + a1;
    __syncthreads();
    for (int off = 1; off < 256; off <<= 1) {
        int v = (t >= off) ? sc[t - off] : 0;
        __syncthreads();
        sc[t] += v;
        __syncthreads();
    }
    int excl = (t == 0) ? 0 : sc[t - 1];
    lpos[2 * t] = excl;
    lpos[2 * t + 1] = excl + a0;
    lcur[2 * t] = excl;
    lcur[2 * t + 1] = excl + a0;
    __syncthreads();
    int bbase = bucket_base[b];
    int total = bucket_base[b + 1] - bbase;
    if (total > BSTAGE) total = BSTAGE;
    int n0 = b * 512;
    for (int i = t; i < 512; i += 256) {
        int n = n0 + i;
        if (n < N_NODES) {
            row_start[n] = bbase + lpos[i];
            int dg = ldeg[i];
            invc[n] = 1.0f / (float)(dg > 0 ? dg : 1);
        }
    }
    if (b == 0 && t == 0) row_start[N_NODES] = bucket_base[NB];
    for (int s = 0; s < 8; s++) {
        int c = cnt[s];
        const int* base = pairs + (size_t)(b * 8 + s) * SUBCAP;
        for (int i = t; i < c; i += 256) {
            int v = base[i];
            int p = atomicAdd(&lcur[v & 511], 1);
            if (p < BSTAGE) stage[p] = v >> 9;
        }
    }
    __syncthreads();
    for (int i = t; i < total; i += 256) col[bbase + i] = stage[i];
}

// ---------------- aggregation: mean over in-neighbors ----------------
__global__ void __launch_bounds__(256)
k_agg(const float4* __restrict__ X4, const int* __restrict__ row_start,
      const int* __restrict__ col, const float* __restrict__ inv_cnt,
      float4* __restrict__ M4) {
    int t = blockIdx.x * blockDim.x + threadIdx.x;
    int sub = t & 15;          // feature quad within node
    int n = t >> 4;            // node id
    if (n >= N_NODES) return;
    int s = row_start[n];
    int e = row_start[n + 1];
    float4 acc = make_float4(0.f, 0.f, 0.f, 0.f);
    int j = s;
    for (; j + 4 <= e; j += 4) {
        int c0 = col[j + 0];
        int c1 = col[j + 1];
        int c2 = col[j + 2];
        int c3 = col[j + 3];
        float4 a = X4[(size_t)c0 * 16 + sub];
        float4 b = X4[(size_t)c1 * 16 + sub];
        float4 c = X4[(size_t)c2 * 16 + sub];
        float4 d = X4[(size_t)c3 * 16 + sub];
        acc.x += (a.x + b.x) + (c.x + d.x);
        acc.y += (a.y + b.y) + (c.y + d.y);
        acc.z += (a.z + b.z) + (c.z + d.z);
        acc.w += (a.w + b.w) + (c.w + d.w);
    }
    for (; j < e; j++) {
        float4 a = X4[(size_t)col[j] * 16 + sub];
        acc.x += a.x; acc.y += a.y; acc.z += a.z; acc.w += a.w;
    }
    float ic = inv_cnt[n];
    acc.x *= ic; acc.y *= ic; acc.z *= ic; acc.w *= ic;
    M4[(size_t)n * 16 + sub] = acc;
}

// ---------------- fused linear: out = M*Wl^T + X*Wr^T + b (opt relu) -------------
#define WROW 68
__global__ void __launch_bounds__(256)
k_linear(const float4* __restrict__ Ma4, const float4* __restrict__ Xa4,
         const float* __restrict__ Wl, const float* __restrict__ Wr,
         const float* __restrict__ bias, float4* __restrict__ out4, int do_relu) {
    __shared__ float wlT[D * WROW];
    __shared__ float wrT[D * WROW];
    int t = threadIdx.x;
    for (int i = t; i < D * D; i += 256) {
        int oc = i >> 6, k = i & 63;
        wlT[k * WROW + oc] = Wl[i];
        wrT[k * WROW + oc] = Wr[i];
    }
    __syncthreads();

    int lane = t & 63;
    int ocb = (t >> 6) * 16;
    int n = blockIdx.x * 64 + lane;
    if (n >= N_NODES) return;

    const float4* mrow = Ma4 + (size_t)n * (D / 4);
    const float4* xrow = Xa4 + (size_t)n * (D / 4);

    float acc[16];
#pragma unroll
    for (int o = 0; o < 16; o++) acc[o] = bias[ocb + o];

#pragma unroll 4
    for (int k4 = 0; k4 < D / 4; k4++) {
        float4 mv = mrow[k4];
        float4 xv = xrow[k4];
        const float* mp = (const float*)&mv;
        const float* xp = (const float*)&xv;
#pragma unroll
        for (int j = 0; j < 4; j++) {
            int k = k4 * 4 + j;
            const float4* wl4 = (const float4*)&wlT[k * WROW + ocb];
            const float4* wr4 = (const float4*)&wrT[k * WROW + ocb];
            float mj = mp[j];
            float xj = xp[j];
#pragma unroll
            for (int og = 0; og < 4; og++) {
                float4 wlv = wl4[og];
                float4 wrv = wr4[og];
                acc[og * 4 + 0] = fmaf(mj, wlv.x, fmaf(xj, wrv.x, acc[og * 4 + 0]));
                acc[og * 4 + 1] = fmaf(mj, wlv.y, fmaf(xj, wrv.y, acc[og * 4 + 1]));
                acc[og * 4 + 2] = fmaf(mj, wlv.z, fmaf(xj, wrv.z, acc[og * 4 + 2]));
                acc[og * 4 + 3] = fmaf(mj, wlv.w, fmaf(xj, wrv.w, acc[og * 4 + 3]));
            }
        }
    }

    if (do_relu) {
#pragma unroll
        for (int o = 0; o < 16; o++) acc[o] = fmaxf(acc[o], 0.f);
    }
    float4* orow = out4 + (size_t)n * (D / 4) + ocb / 4;
#pragma unroll
    for (int og = 0; og < 4; og++) {
        orow[og] = make_float4(acc[og * 4 + 0], acc[og * 4 + 1],
                               acc[og * 4 + 2], acc[og * 4 + 3]);
    }
}

// ---------------- launch ----------------
extern "C" void kernel_launch(void* const* d_in, const int* in_sizes, int n_in,
                              void* d_out, int out_size, void* d_ws, size_t ws_size,
                              hipStream_t stream) {
    const float* x   = (const float*)d_in[0];
    const int*   ei  = (const int*)d_in[1];
    const float* W1l = (const float*)d_in[2];
    const float* b1  = (const float*)d_in[3];
    const float* W1r = (const float*)d_in[4];
    const float* W2l = (const float*)d_in[5];
    const float* b2  = (const float*)d_in[6];
    const float* W2r = (const float*)d_in[7];
    float* out = (float*)d_out;

    char* ws = (char*)d_ws;
    size_t off = 0;
    auto alloc = [&](size_t bytes) -> char* {
        char* p = ws + off;
        off = (off + bytes + 255) & ~(size_t)255;
        return p;
    };
    int*   row_start   = (int*)alloc((size_t)(N_NODES + 1) * 4);
    int*   col         = (int*)alloc((size_t)N_EDGES * 4);
    float* invc        = (float*)alloc((size_t)N_NODES * 4);
    int*   subcur      = (int*)alloc((size_t)NB * 8 * 4);
    int*   bucket_base = (int*)alloc((size_t)(NB + 1) * 4);
    float* mbuf        = (float*)alloc((size_t)N_NODES * D * 4);
    float* hbuf        = (float*)alloc((size_t)N_NODES * D * 4);
    // pairs staging (6.4 MB) aliases mbuf (25.6 MB): consumed by k_bucketB
    // before k_agg writes mbuf.
    int* pairs = (int*)mbuf;

    // CSR build via two-phase bucket sort (dense writes, low atomic contention)
    hipMemsetAsync(subcur, 0, (size_t)NB * 8 * 4, stream);
    k_bucketA<<<ABLOCKS, 256, 0, stream>>>(ei, subcur, pairs);
    k_bscan<<<1, 256, 0, stream>>>(subcur, bucket_base);
    k_bucketB<<<NB, 256, 0, stream>>>(subcur, pairs, bucket_base, col, row_start, invc);

    const int agg_blocks = (N_NODES * 16 + 255) / 256;   // 16 lanes per node
    const int lin_blocks = (N_NODES + 63) / 64;          // 64 nodes per block

    // layer 1
    k_agg<<<agg_blocks, 256, 0, stream>>>((const float4*)x, row_start, col, invc,
                                          (float4*)mbuf);
    k_linear<<<lin_blocks, 256, 0, stream>>>((const float4*)mbuf, (const float4*)x,
                                             W1l, W1r, b1, (float4*)hbuf, 1);
    // layer 2
    k_agg<<<agg_blocks, 256, 0, stream>>>((const float4*)hbuf, row_start, col, invc,
                                          (float4*)mbuf);
    k_linear<<<lin_blocks, 256, 0, stream>>>((const float4*)mbuf, (const float4*)hbuf,
                                             W2l, W2r, b2, (float4*)out, 0);
}